// Round 4
// baseline (571.425 us; speedup 1.0000x reference)
//
#include <hip/hip_runtime.h>

#define NN 20000
#define NP 20096   // padded rows (multiple of 128)
#define NE 320000
#define DD 512

typedef __bf16 bf16x8 __attribute__((ext_vector_type(8)));
typedef float f32x4 __attribute__((ext_vector_type(4)));
typedef unsigned short u16;

__device__ __forceinline__ float sigmoidf_(float x) { return 1.f / (1.f + expf(-x)); }

__device__ __forceinline__ unsigned bf16pair(float a, float b) {
  unsigned ua = __builtin_bit_cast(unsigned, a);
  unsigned ub = __builtin_bit_cast(unsigned, b);
  ua = (ua + 0x7FFFu + ((ua >> 16) & 1u)) >> 16;
  ub = (ub + 0x7FFFu + ((ub >> 16) & 1u)) >> 16;
  return ua | (ub << 16);
}
__device__ __forceinline__ u16 bf16one(float a) {
  unsigned ua = __builtin_bit_cast(unsigned, a);
  return (u16)((ua + 0x7FFFu + ((ua >> 16) & 1u)) >> 16);
}
__device__ __forceinline__ float bflo(unsigned w) { return __builtin_bit_cast(float, w << 16); }
__device__ __forceinline__ float bfhi(unsigned w) { return __builtin_bit_cast(float, w & 0xFFFF0000u); }
__device__ __forceinline__ float bf2f(u16 v) { return __builtin_bit_cast(float, (unsigned)v << 16); }

__device__ __forceinline__ void gload16(const void* g, void* l) {
  __builtin_amdgcn_global_load_lds(
      (const __attribute__((address_space(1))) unsigned int*)g,
      (__attribute__((address_space(3))) unsigned int*)l, 16, 0, 0);
}

// ---------------- degree / norm / CSR ----------------
__global__ void k_init(float* deg, int* cnt) {
  int i = blockIdx.x * 256 + threadIdx.x;
  if (i < NN) { deg[i] = 1.0f; cnt[i] = 0; }
}

__global__ void k_accum(const int* col, const float* w, float* deg, int* cnt) {
  int e = blockIdx.x * 256 + threadIdx.x;
  if (e < NE) {
    int c = col[e];
    atomicAdd(&deg[c], w[e]);
    atomicAdd(&cnt[c], 1);
  }
}

__global__ void k_dinv(const float* deg, float* dinv) {
  int i = blockIdx.x * 256 + threadIdx.x;
  if (i < NN) dinv[i] = rsqrtf(deg[i]);
}

__global__ void k_scan(const int* cnt, int* ptr, int* pos) {
  __shared__ int sdata[1024];
  const int ITEMS = (NN + 1023) / 1024;
  int tid = threadIdx.x;
  int base = tid * ITEMS;
  int s = 0;
  for (int j = 0; j < ITEMS; ++j) { int i = base + j; if (i < NN) s += cnt[i]; }
  sdata[tid] = s;
  __syncthreads();
  for (int off = 1; off < 1024; off <<= 1) {
    int v = 0;
    if (tid >= off) v = sdata[tid - off];
    __syncthreads();
    sdata[tid] += v;
    __syncthreads();
  }
  int run = (tid == 0) ? 0 : sdata[tid - 1];
  for (int j = 0; j < ITEMS; ++j) {
    int i = base + j;
    if (i < NN) { ptr[i] = run; pos[i] = run; run += cnt[i]; }
  }
  if (tid == 0) ptr[NN] = NE;
}

__global__ void k_scatter(const int* row, const int* col, const float* w, const float* dinv,
                          int* pos, int* erow, float* enorm) {
  int e = blockIdx.x * 256 + threadIdx.x;
  if (e < NE) {
    int r = row[e], c = col[e];
    int slot = atomicAdd(&pos[c], 1);
    erow[slot] = r;
    enorm[slot] = dinv[r] * w[e] * dinv[c];
  }
}

// ---------------- conversions ----------------
__global__ void k_cvt_bf16(const float* __restrict__ src, u16* __restrict__ dst, int n8) {
  int i = blockIdx.x * 256 + threadIdx.x;
  if (i >= n8) return;
  const float4* s = (const float4*)src;
  float4 v0 = s[i * 2], v1 = s[i * 2 + 1];
  uint4 o;
  o.x = bf16pair(v0.x, v0.y);
  o.y = bf16pair(v0.z, v0.w);
  o.z = bf16pair(v1.x, v1.y);
  o.w = bf16pair(v1.z, v1.w);
  ((uint4*)dst)[i] = o;
}

// W [512][512] f32 -> dst[n*stride + k] bf16 (transposed); dst pre-offset by caller
__global__ void k_wt_gen(const float* __restrict__ W, u16* __restrict__ dst, int dstStride) {
  __shared__ float t[32][33];
  int tx = threadIdx.x, ty = threadIdx.y;  // (32,8)
  int kb = blockIdx.x * 32, nb = blockIdx.y * 32;
#pragma unroll
  for (int i = 0; i < 4; ++i)
    t[ty * 4 + i][tx] = W[(size_t)(kb + ty * 4 + i) * 512 + nb + tx];
  __syncthreads();
#pragma unroll
  for (int i = 0; i < 4; ++i)
    dst[(size_t)(nb + ty * 4 + i) * dstStride + kb + tx] = bf16one(t[tx][ty * 4 + i]);
}

// ---------------- XCD-sliced sparse aggregation ----------------
// slice = bid%8 (one per XCD, empirically); each slice covers 64 bf16 cols (128B).
// wave = one node; lanes 0-31 gather X-slice, lanes 32-63 gather H-slice.
// writes AXH[node][1024]: cols 0-511 = Agg(X), 512-1023 = Agg(H).
__global__ __launch_bounds__(256) void k_agg_dual_s(const u16* __restrict__ Xb,
                                                    const u16* __restrict__ Hb,
                                                    const int* __restrict__ ptr,
                                                    const int* __restrict__ erow,
                                                    const float* __restrict__ enorm,
                                                    const float* __restrict__ dinv,
                                                    u16* __restrict__ AXH) {
  int bid = blockIdx.x;
  int slice = bid & 7, nb = bid >> 3;
  int w = threadIdx.x >> 6, lane = threadIdx.x & 63;
  int node = nb * 4 + w;
  int l = lane & 31;
  bool isH = lane >= 32;
  const unsigned* src = (const unsigned*)(isH ? Hb : Xb);
  int off = slice * 32 + l;
  float a0, a1;
  float s = dinv[node], s2 = s * s;
  { unsigned u = src[(size_t)node * 256 + off]; a0 = s2 * bflo(u); a1 = s2 * bfhi(u); }
  int e = ptr[node], e1 = ptr[node + 1];
  for (; e + 2 <= e1; e += 2) {
    int r0 = erow[e], r1 = erow[e + 1];
    float n0 = enorm[e], n1 = enorm[e + 1];
    unsigned u0 = src[(size_t)r0 * 256 + off];
    unsigned u1 = src[(size_t)r1 * 256 + off];
    a0 += n0 * bflo(u0); a1 += n0 * bfhi(u0);
    a0 += n1 * bflo(u1); a1 += n1 * bfhi(u1);
  }
  if (e < e1) {
    int r0 = erow[e]; float n0 = enorm[e];
    unsigned u0 = src[(size_t)r0 * 256 + off];
    a0 += n0 * bflo(u0); a1 += n0 * bfhi(u0);
  }
  ((unsigned*)AXH)[(size_t)node * 512 + (isH ? 256 : 0) + off] = bf16pair(a0, a1);
}

// single-matrix sliced agg: half-waves take alternating edges, shfl-combine.
__global__ __launch_bounds__(256) void k_agg_hr_s(const u16* __restrict__ Sb,
                                                  const int* __restrict__ ptr,
                                                  const int* __restrict__ erow,
                                                  const float* __restrict__ enorm,
                                                  const float* __restrict__ dinv,
                                                  u16* __restrict__ Ab) {
  int bid = blockIdx.x;
  int slice = bid & 7, nb = bid >> 3;
  int w = threadIdx.x >> 6, lane = threadIdx.x & 63;
  int node = nb * 4 + w;
  int l = lane & 31;
  bool hi = lane >= 32;
  const unsigned* S = (const unsigned*)Sb;
  int off = slice * 32 + l;
  float a0 = 0.f, a1 = 0.f;
  float s = dinv[node], s2 = s * s;
  if (!hi) {
    unsigned u = S[(size_t)node * 256 + off];
    a0 = s2 * bflo(u); a1 = s2 * bfhi(u);
  }
  int e1 = ptr[node + 1];
  for (int e = ptr[node] + (hi ? 1 : 0); e < e1; e += 2) {
    int r = erow[e]; float nm = enorm[e];
    unsigned u = S[(size_t)r * 256 + off];
    a0 += nm * bflo(u); a1 += nm * bfhi(u);
  }
  a0 += __shfl_down(a0, 32, 64);
  a1 += __shfl_down(a1, 32, 64);
  if (!hi) ((unsigned*)Ab)[(size_t)node * 256 + off] = bf16pair(a0, a1);
}

// ---------------- fused MFMA GEMM, 2-phase dbuf, XCD-chunked blocks ----------------
// MODE 0: A=AXH [NP][1024]. cols 0-511: Z=sigma -> Zb; 512-1023: HR -> HRb; 1024-1535: Mx -> Mxb.
//         B for c<8: Wcat[1024][1024] (n-major, k 0-511=Wx*, 512-1023=Wh*); c>=8: Wxh_t[512][512].
// MODE 1: A=AHRb [NP][512], B=Whh_t[512][512]; out = z*H + (1-z)*tanh(acc + Mx + bxh + bhh).
template <int MODE>
__global__ __launch_bounds__(256) void k_gemm2(
    const u16* __restrict__ A, const u16* __restrict__ Wc, const u16* __restrict__ Wx,
    const float* __restrict__ bz1, const float* __restrict__ bz2,
    const float* __restrict__ br1, const float* __restrict__ br2,
    const float* __restrict__ bh1, const float* __restrict__ bh2,
    const float* __restrict__ Hf,
    u16* __restrict__ Zb, u16* __restrict__ HRb, u16* __restrict__ Mxb,
    const u16* __restrict__ Zr, const u16* __restrict__ Mxr,
    float* __restrict__ out) {
  extern __shared__ unsigned char smem[];  // 2 x (A 16KB | B 16KB) = 64KB
  const int tid = threadIdx.x;
  const int lane = tid & 63, w = tid >> 6;
  const int wr = w >> 1, wc = w & 1;

  // bijective XCD-chunked mapping (m204): same row-block's col-blocks stay on one XCD
  const int NB = (MODE == 0) ? 1884 : 628;
  const int NCB = (MODE == 0) ? 12 : 4;
  const int q = NB >> 3, r8 = NB & 7;
  const int x = blockIdx.x & 7, ii = blockIdx.x >> 3;
  const int start = (x < r8) ? x * (q + 1) : r8 * (q + 1) + (x - r8) * q;
  const int wk = start + ii;
  const int rowBase = (wk / NCB) * 128;
  const int c = wk % NCB;
  const int colBase = c * 128;

  int NK;
  size_t strideA, strideB;
  const u16* Bb;
  if (MODE == 0) {
    strideA = 2048;
    if (c < 8) { Bb = Wc + (size_t)c * 128 * 1024; strideB = 2048; NK = 16; }
    else       { Bb = Wx + (size_t)(c - 8) * 128 * 512; strideB = 1024; NK = 8; }
  } else {
    strideA = 1024;
    Bb = Wc + (size_t)c * 128 * 512;
    strideB = 1024;
    NK = 8;
  }

  f32x4 acc[4][4] = {};

  const int lrow = lane & 15;
  const int lkb = (lane >> 4) << 4;
  const int swz = (lane & 7) << 4;
  const int srow0 = w * 32 + (lane >> 3);
  const int scol = (((lane & 7) ^ (lane >> 3)) << 4);
  const char* Ath = (const char*)A + (size_t)(rowBase + srow0) * strideA + scol;
  const char* Bth = (const char*)Bb + (size_t)srow0 * strideB + scol;

  auto STAGE = [&](int kt, int buf) {
    int bo = buf << 15;
    size_t ko = (size_t)kt << 7;  // kt*128 bytes (64 bf16 cols)
#pragma unroll
    for (int t = 0; t < 4; ++t) {
      gload16(Ath + (size_t)(t * 8) * strideA + ko, &smem[bo + w * 4096 + t * 1024]);
      gload16(Bth + (size_t)(t * 8) * strideB + ko, &smem[bo + 16384 + w * 4096 + t * 1024]);
    }
  };
  auto COMPUTE = [&](int buf) {
    int bo = buf << 15;
#pragma unroll
    for (int ks = 0; ks < 2; ++ks) {
      bf16x8 af[4], bfr[4];
#pragma unroll
      for (int fm = 0; fm < 4; ++fm) {
        int row = wr * 64 + fm * 16 + lrow;
        af[fm] = *(const bf16x8*)&smem[bo + row * 128 + (((ks << 6) + lkb) ^ swz)];
      }
#pragma unroll
      for (int fn = 0; fn < 4; ++fn) {
        int row = wc * 64 + fn * 16 + lrow;
        bfr[fn] = *(const bf16x8*)&smem[bo + 16384 + row * 128 + (((ks << 6) + lkb) ^ swz)];
      }
#pragma unroll
      for (int fm = 0; fm < 4; ++fm)
#pragma unroll
        for (int fn = 0; fn < 4; ++fn)
          acc[fm][fn] = __builtin_amdgcn_mfma_f32_16x16x32_bf16(af[fm], bfr[fn], acc[fm][fn], 0, 0, 0);
    }
  };

  // T3 minimum 2-phase: STAGE(next) issued before COMPUTE(cur); one vmcnt(0)+barrier per step
  STAGE(0, 0);
  asm volatile("s_waitcnt vmcnt(0)" ::: "memory");
  __builtin_amdgcn_s_barrier();
  asm volatile("" ::: "memory");
  for (int kt = 0; kt < NK; ++kt) {
    if (kt + 1 < NK) STAGE(kt + 1, (kt + 1) & 1);
    COMPUTE(kt & 1);
    asm volatile("s_waitcnt vmcnt(0)" ::: "memory");
    __builtin_amdgcn_s_barrier();
    asm volatile("" ::: "memory");
  }

  // epilogue: C/D layout col=lane&15, row=(lane>>4)*4+reg
#pragma unroll
  for (int fm = 0; fm < 4; ++fm) {
    int rbase = rowBase + wr * 64 + fm * 16 + ((lane >> 4) << 2);
#pragma unroll
    for (int fn = 0; fn < 4; ++fn) {
      int col = colBase + wc * 64 + fn * 16 + lrow;
      if (MODE == 0) {
        if (colBase < 512) {
          float bb = bz1[col] + bz2[col];
#pragma unroll
          for (int rr = 0; rr < 4; ++rr) {
            int row = rbase + rr;
            if (row < NN) Zb[(size_t)row * 512 + col] = bf16one(sigmoidf_(acc[fm][fn][rr] + bb));
          }
        } else if (colBase < 1024) {
          int cc = col - 512;
          float bb = br1[cc] + br2[cc];
#pragma unroll
          for (int rr = 0; rr < 4; ++rr) {
            int row = rbase + rr;
            if (row < NN) {
              size_t idx = (size_t)row * 512 + cc;
              HRb[idx] = bf16one(Hf[idx] * sigmoidf_(acc[fm][fn][rr] + bb));
            }
          }
        } else {
          int cc = col - 1024;
#pragma unroll
          for (int rr = 0; rr < 4; ++rr) {
            int row = rbase + rr;
            if (row < NN) Mxb[(size_t)row * 512 + cc] = bf16one(acc[fm][fn][rr]);
          }
        }
      } else {
        float bb = bh1[col] + bh2[col];
#pragma unroll
        for (int rr = 0; rr < 4; ++rr) {
          int row = rbase + rr;
          if (row < NN) {
            size_t idx = (size_t)row * 512 + col;
            float a = acc[fm][fn][rr] + bb + bf2f(Mxr[idx]);
            float t = tanhf(a);
            float z = bf2f(Zr[idx]);
            out[idx] = z * Hf[idx] + (1.f - z) * t;
          }
        }
      }
    }
  }
}

extern "C" void kernel_launch(void* const* d_in, const int* in_sizes, int n_in,
                              void* d_out, int out_size, void* d_ws, size_t ws_size,
                              hipStream_t stream) {
  const float* X   = (const float*)d_in[0];
  const int*   ei  = (const int*)d_in[1];
  const float* ew  = (const float*)d_in[2];
  const float* H   = (const float*)d_in[3];
  const float* Wxz = (const float*)d_in[4];  const float* bxz = (const float*)d_in[5];
  const float* Whz = (const float*)d_in[6];  const float* bhz = (const float*)d_in[7];
  const float* Wxr = (const float*)d_in[8];  const float* bxr = (const float*)d_in[9];
  const float* Whr = (const float*)d_in[10]; const float* bhr = (const float*)d_in[11];
  const float* Wxh = (const float*)d_in[12]; const float* bxh = (const float*)d_in[13];
  const float* Whh = (const float*)d_in[14]; const float* bhh = (const float*)d_in[15];
  const int* row = ei;
  const int* col = ei + NE;
  float* out = (float*)d_out;

  char* base = (char*)d_ws;
  size_t o = 0;
  auto alloc = [&](size_t b) { char* p = base + o; o += (b + 255) & ~(size_t)255; return p; };
  u16* Xb   = (u16*)alloc((size_t)NP * DD * 2);  // aliases Mxb (Xb dead after agg_dual)
  u16* Hb   = (u16*)alloc((size_t)NP * DD * 2);  // aliases HRb (Hb dead after agg_dual)
  u16* AXH  = (u16*)alloc((size_t)NP * 1024 * 2);
  u16* AHRb = (u16*)alloc((size_t)NP * DD * 2);
  u16* Zb   = (u16*)alloc((size_t)NP * DD * 2);
  u16* Wcat = (u16*)alloc((size_t)1024 * 1024 * 2);
  u16* Wxh_t= (u16*)alloc((size_t)512 * 512 * 2);
  u16* Whh_t= (u16*)alloc((size_t)512 * 512 * 2);
  float* deg  = (float*)alloc(NN * 4);
  float* dinv = (float*)alloc(NN * 4);
  int*   cnt  = (int*)alloc(NN * 4);
  int*   ptr  = (int*)alloc((NN + 1) * 4);
  int*   pos  = (int*)alloc(NN * 4);
  int*   erow = (int*)alloc(NE * 4);
  float* enorm= (float*)alloc(NE * 4);
  u16* Mxb = Xb;
  u16* HRb = Hb;

  dim3 b256(256);
  int gN = (NN + 255) / 256;
  int gE = (NE + 255) / 256;

  // graph normalization + CSR build
  k_init<<<gN, b256, 0, stream>>>(deg, cnt);
  k_accum<<<gE, b256, 0, stream>>>(col, ew, deg, cnt);
  k_dinv<<<gN, b256, 0, stream>>>(deg, dinv);
  k_scan<<<1, 1024, 0, stream>>>(cnt, ptr, pos);
  k_scatter<<<gE, b256, 0, stream>>>(row, col, ew, dinv, pos, erow, enorm);

  // conversions + weight packing
  int n8 = NN * DD / 8;
  k_cvt_bf16<<<(n8 + 255) / 256, b256, 0, stream>>>(X, Xb, n8);
  k_cvt_bf16<<<(n8 + 255) / 256, b256, 0, stream>>>(H, Hb, n8);
  dim3 wtb(32, 8), wtg(16, 16);
  k_wt_gen<<<wtg, wtb, 0, stream>>>(Wxz, Wcat, 1024);                    // c<512, k<512
  k_wt_gen<<<wtg, wtb, 0, stream>>>(Whz, Wcat + 512, 1024);              // c<512, k>=512
  k_wt_gen<<<wtg, wtb, 0, stream>>>(Wxr, Wcat + (size_t)512 * 1024, 1024);       // c>=512, k<512
  k_wt_gen<<<wtg, wtb, 0, stream>>>(Whr, Wcat + (size_t)512 * 1024 + 512, 1024); // c>=512, k>=512
  k_wt_gen<<<wtg, wtb, 0, stream>>>(Wxh, Wxh_t, 512);
  k_wt_gen<<<wtg, wtb, 0, stream>>>(Whh, Whh_t, 512);

  // AXH = [Agg(X) | Agg(H)], XCD-sliced
  k_agg_dual_s<<<40000, b256, 0, stream>>>(Xb, Hb, ptr, erow, enorm, dinv, AXH);

  // phase-1 fused GEMM: Z, HR, Mx
  k_gemm2<0><<<1884, b256, 65536, stream>>>(AXH, Wcat, Wxh_t,
                                            bxz, bhz, bxr, bhr, nullptr, nullptr,
                                            H, Zb, HRb, Mxb, nullptr, nullptr, nullptr);

  // AHR = Agg(HR), XCD-sliced
  k_agg_hr_s<<<40000, b256, 0, stream>>>(HRb, ptr, erow, enorm, dinv, AHRb);

  // final GEMM: out = Z*H + (1-Z)*tanh(Mx + AHR@Whh + bxh + bhh)
  k_gemm2<1><<<628, b256, 65536, stream>>>(AHRb, Whh_t, nullptr,
                                           nullptr, nullptr, nullptr, nullptr, bxh, bhh,
                                           H, nullptr, nullptr, nullptr, Zb, Mxb, out);
}

// Round 5
// 418.928 us; speedup vs baseline: 1.3640x; 1.3640x over previous
//
#include <hip/hip_runtime.h>

#define NN 20000
#define NP 20096   // padded rows (multiple of 128)
#define NE 320000
#define DD 512

typedef __bf16 bf16x8 __attribute__((ext_vector_type(8)));
typedef float f32x4 __attribute__((ext_vector_type(4)));
typedef unsigned short u16;

__device__ __forceinline__ float sigmoidf_(float x) { return 1.f / (1.f + expf(-x)); }

__device__ __forceinline__ unsigned bf16pair(float a, float b) {
  unsigned ua = __builtin_bit_cast(unsigned, a);
  unsigned ub = __builtin_bit_cast(unsigned, b);
  ua = (ua + 0x7FFFu + ((ua >> 16) & 1u)) >> 16;
  ub = (ub + 0x7FFFu + ((ub >> 16) & 1u)) >> 16;
  return ua | (ub << 16);
}
__device__ __forceinline__ u16 bf16one(float a) {
  unsigned ua = __builtin_bit_cast(unsigned, a);
  return (u16)((ua + 0x7FFFu + ((ua >> 16) & 1u)) >> 16);
}
__device__ __forceinline__ float bflo(unsigned w) { return __builtin_bit_cast(float, w << 16); }
__device__ __forceinline__ float bfhi(unsigned w) { return __builtin_bit_cast(float, w & 0xFFFF0000u); }

__device__ __forceinline__ void gload16(const void* g, void* l) {
  __builtin_amdgcn_global_load_lds(
      (const __attribute__((address_space(1))) unsigned int*)g,
      (__attribute__((address_space(3))) unsigned int*)l, 16, 0, 0);
}

// ---------------- degree / norm / CSR ----------------
__global__ void k_init(float* deg, int* cnt) {
  int i = blockIdx.x * 256 + threadIdx.x;
  if (i < NN) { deg[i] = 1.0f; cnt[i] = 0; }
}

__global__ void k_accum(const int* col, const float* w, float* deg, int* cnt) {
  int e = blockIdx.x * 256 + threadIdx.x;
  if (e < NE) {
    int c = col[e];
    atomicAdd(&deg[c], w[e]);
    atomicAdd(&cnt[c], 1);
  }
}

__global__ void k_dinv(const float* deg, float* dinv) {
  int i = blockIdx.x * 256 + threadIdx.x;
  if (i < NN) dinv[i] = rsqrtf(deg[i]);
}

__global__ void k_scan(const int* cnt, int* ptr, int* pos) {
  __shared__ int sdata[1024];
  const int ITEMS = (NN + 1023) / 1024;
  int tid = threadIdx.x;
  int base = tid * ITEMS;
  int s = 0;
  for (int j = 0; j < ITEMS; ++j) { int i = base + j; if (i < NN) s += cnt[i]; }
  sdata[tid] = s;
  __syncthreads();
  for (int off = 1; off < 1024; off <<= 1) {
    int v = 0;
    if (tid >= off) v = sdata[tid - off];
    __syncthreads();
    sdata[tid] += v;
    __syncthreads();
  }
  int run = (tid == 0) ? 0 : sdata[tid - 1];
  for (int j = 0; j < ITEMS; ++j) {
    int i = base + j;
    if (i < NN) { ptr[i] = run; pos[i] = run; run += cnt[i]; }
  }
  if (tid == 0) ptr[NN] = NE;
}

__global__ void k_scatter(const int* row, const int* col, const float* w, const float* dinv,
                          int* pos, int* erow, float* enorm) {
  int e = blockIdx.x * 256 + threadIdx.x;
  if (e < NE) {
    int r = row[e], c = col[e];
    int slot = atomicAdd(&pos[c], 1);
    erow[slot] = r;
    enorm[slot] = dinv[r] * w[e] * dinv[c];
  }
}

// ---------------- conversions ----------------
__global__ void k_cvt_bf16(const float* __restrict__ src, u16* __restrict__ dst, int n8) {
  int i = blockIdx.x * 256 + threadIdx.x;
  if (i >= n8) return;
  const float4* s = (const float4*)src;
  float4 v0 = s[i * 2], v1 = s[i * 2 + 1];
  uint4 o;
  o.x = bf16pair(v0.x, v0.y);
  o.y = bf16pair(v0.z, v0.w);
  o.z = bf16pair(v1.x, v1.y);
  o.w = bf16pair(v1.z, v1.w);
  ((uint4*)dst)[i] = o;
}

// W [512][512] f32 -> Wt [n][k] bf16 (transposed)
__global__ void k_wt(const float* __restrict__ W, u16* __restrict__ Wt) {
  __shared__ float t[32][33];
  int tx = threadIdx.x, ty = threadIdx.y;  // (32,8)
  int kb = blockIdx.x * 32, nb = blockIdx.y * 32;
#pragma unroll
  for (int i = 0; i < 4; ++i)
    t[ty * 4 + i][tx] = W[(size_t)(kb + ty * 4 + i) * 512 + nb + tx];
  __syncthreads();
#pragma unroll
  for (int i = 0; i < 4; ++i)
    Wt[(size_t)(nb + ty * 4 + i) * 512 + kb + tx] = bf16one(t[tx][ty * 4 + i]);
}

// ---------------- XCD-sliced aggregation, 16B/lane, 8 edges in parallel ----------
// slice = bid&7 (XCD-local 128B column slice); wave = one node.
// lane = g*8 + cl: group g in [0,8) processes item (it0+g); cl indexes 16B within slice.
// item 0 = self-loop (weight dinv^2), item i>0 = CSR edge (pe+i-1).
// Tail: shfl_xor butterfly over strides 8/16/32 sums the 8 groups.
__global__ __launch_bounds__(256) void k_agg_dual_s2(const u16* __restrict__ Xb,
                                                     const u16* __restrict__ Hb,
                                                     const int* __restrict__ ptr,
                                                     const int* __restrict__ erow,
                                                     const float* __restrict__ enorm,
                                                     const float* __restrict__ dinv,
                                                     u16* __restrict__ AXb,
                                                     u16* __restrict__ AHb) {
  int bid = blockIdx.x;
  int slice = bid & 7, nb = bid >> 3;
  int w = threadIdx.x >> 6, lane = threadIdx.x & 63;
  int node = nb * 4 + w;
  int g = lane >> 3, cl = lane & 7;
  int soff = slice * 8 + cl;                 // uint4 index within a 64-uint4 row
  const uint4* X4 = (const uint4*)Xb;
  const uint4* H4 = (const uint4*)Hb;
  float s = dinv[node], s2 = s * s;
  int pe = ptr[node];
  int items = ptr[node + 1] - pe + 1;        // self + deg

  float ax[8] = {}, ah[8] = {};
  auto accum = [&](float nm, uint4 xv, uint4 hv) {
    unsigned xw[4] = {xv.x, xv.y, xv.z, xv.w};
    unsigned hw[4] = {hv.x, hv.y, hv.z, hv.w};
#pragma unroll
    for (int j = 0; j < 4; ++j) {
      ax[2 * j]     += nm * bflo(xw[j]);
      ax[2 * j + 1] += nm * bfhi(xw[j]);
      ah[2 * j]     += nm * bflo(hw[j]);
      ah[2 * j + 1] += nm * bfhi(hw[j]);
    }
  };

  for (int it0 = 0; it0 < items; it0 += 16) {
    int itA = it0 + g, itB = it0 + 8 + g;
    bool vA = itA < items, vB = itB < items;
    int rA = node; float nA = 0.f;
    if (vA) { if (itA == 0) { nA = s2; } else { rA = erow[pe + itA - 1]; nA = enorm[pe + itA - 1]; } }
    int rB = node; float nB = 0.f;
    if (vB) { rB = erow[pe + itB - 1]; nB = enorm[pe + itB - 1]; }
    uint4 xA = X4[(size_t)rA * 64 + soff];
    uint4 hA = H4[(size_t)rA * 64 + soff];
    uint4 xB = X4[(size_t)rB * 64 + soff];
    uint4 hB = H4[(size_t)rB * 64 + soff];
    accum(nA, xA, hA);
    accum(nB, xB, hB);
  }

#pragma unroll
  for (int st = 8; st < 64; st <<= 1) {
#pragma unroll
    for (int j = 0; j < 8; ++j) {
      ax[j] += __shfl_xor(ax[j], st, 64);
      ah[j] += __shfl_xor(ah[j], st, 64);
    }
  }

  if (g == 0) {
    uint4 ox;
    ox.x = bf16pair(ax[0], ax[1]); ox.y = bf16pair(ax[2], ax[3]);
    ox.z = bf16pair(ax[4], ax[5]); ox.w = bf16pair(ax[6], ax[7]);
    ((uint4*)AXb)[(size_t)node * 64 + soff] = ox;
  } else if (g == 1) {
    uint4 oh;
    oh.x = bf16pair(ah[0], ah[1]); oh.y = bf16pair(ah[2], ah[3]);
    oh.z = bf16pair(ah[4], ah[5]); oh.w = bf16pair(ah[6], ah[7]);
    ((uint4*)AHb)[(size_t)node * 64 + soff] = oh;
  }
}

__global__ __launch_bounds__(256) void k_agg_single_s2(const u16* __restrict__ Sb,
                                                       const int* __restrict__ ptr,
                                                       const int* __restrict__ erow,
                                                       const float* __restrict__ enorm,
                                                       const float* __restrict__ dinv,
                                                       u16* __restrict__ Ab) {
  int bid = blockIdx.x;
  int slice = bid & 7, nb = bid >> 3;
  int w = threadIdx.x >> 6, lane = threadIdx.x & 63;
  int node = nb * 4 + w;
  int g = lane >> 3, cl = lane & 7;
  int soff = slice * 8 + cl;
  const uint4* S4 = (const uint4*)Sb;
  float s = dinv[node], s2 = s * s;
  int pe = ptr[node];
  int items = ptr[node + 1] - pe + 1;

  float ax[8] = {};
  auto accum = [&](float nm, uint4 xv) {
    unsigned xw[4] = {xv.x, xv.y, xv.z, xv.w};
#pragma unroll
    for (int j = 0; j < 4; ++j) {
      ax[2 * j]     += nm * bflo(xw[j]);
      ax[2 * j + 1] += nm * bfhi(xw[j]);
    }
  };

  for (int it0 = 0; it0 < items; it0 += 16) {
    int itA = it0 + g, itB = it0 + 8 + g;
    bool vA = itA < items, vB = itB < items;
    int rA = node; float nA = 0.f;
    if (vA) { if (itA == 0) { nA = s2; } else { rA = erow[pe + itA - 1]; nA = enorm[pe + itA - 1]; } }
    int rB = node; float nB = 0.f;
    if (vB) { rB = erow[pe + itB - 1]; nB = enorm[pe + itB - 1]; }
    uint4 xA = S4[(size_t)rA * 64 + soff];
    uint4 xB = S4[(size_t)rB * 64 + soff];
    accum(nA, xA);
    accum(nB, xB);
  }

#pragma unroll
  for (int st = 8; st < 64; st <<= 1) {
#pragma unroll
    for (int j = 0; j < 8; ++j) ax[j] += __shfl_xor(ax[j], st, 64);
  }

  if (g == 0) {
    uint4 ox;
    ox.x = bf16pair(ax[0], ax[1]); ox.y = bf16pair(ax[2], ax[3]);
    ox.z = bf16pair(ax[4], ax[5]); ox.w = bf16pair(ax[6], ax[7]);
    ((uint4*)Ab)[(size_t)node * 64 + soff] = ox;
  }
}

// ---------------- MFMA GEMM + fused epilogue (round-3 proven structure) --------
// EPI 0: outF = sigmoid(acc+b1+b2)                      (Z, f32)
// EPI 1: outB = bf16(H * sigmoid(acc+b1+b2))            (HR, bf16)
// EPI 2: outF = Z*H + (1-Z)*tanh(acc+b1+b2)             (final)
template <int EPI>
__global__ __launch_bounds__(256) void k_gemm_mfma(
    const u16* __restrict__ A1, const u16* __restrict__ W1t,
    const u16* __restrict__ A2, const u16* __restrict__ W2t,
    const float* __restrict__ b1, const float* __restrict__ b2,
    const float* __restrict__ H, const float* __restrict__ Z,
    float* __restrict__ outF, u16* __restrict__ outB) {
  __shared__ unsigned char smem[32768];  // As 16KB | Bs 16KB
  const int tid = threadIdx.x;
  const int lane = tid & 63, w = tid >> 6;
  const int wr = w >> 1, wc = w & 1;
  const int rowBase = blockIdx.y * 128;
  const int colBase = blockIdx.x * 128;

  f32x4 acc[4][4] = {};

  const int lrow = lane & 15;
  const int lkb = (lane >> 4) << 4;
  const int swz = (lane & 7) << 4;
  const int srow = w * 32 + (lane >> 3);
  const int scol = (((lane & 7) ^ (lane >> 3)) << 4);

  for (int pass = 0; pass < 2; ++pass) {
    const u16* A = pass ? A2 : A1;
    const u16* Wt = pass ? W2t : W1t;
    const char* Abase = (const char*)A + (size_t)(rowBase + srow) * 1024 + scol;
    const char* Bbase = (const char*)Wt + (size_t)(colBase + srow) * 1024 + scol;
    for (int k0 = 0; k0 < 512; k0 += 64) {
      __syncthreads();
#pragma unroll
      for (int t = 0; t < 4; ++t) {
        gload16(Abase + (size_t)t * 8192 + k0 * 2, &smem[w * 4096 + t * 1024]);
        gload16(Bbase + (size_t)t * 8192 + k0 * 2, &smem[16384 + w * 4096 + t * 1024]);
      }
      __syncthreads();
#pragma unroll
      for (int ks = 0; ks < 2; ++ks) {
        bf16x8 af[4], bfr[4];
#pragma unroll
        for (int fm = 0; fm < 4; ++fm) {
          int row = wr * 64 + fm * 16 + lrow;
          int byte = row * 128 + (((ks << 6) + lkb) ^ swz);
          af[fm] = *(const bf16x8*)&smem[byte];
        }
#pragma unroll
        for (int fn = 0; fn < 4; ++fn) {
          int row = wc * 64 + fn * 16 + lrow;
          int byte = 16384 + row * 128 + (((ks << 6) + lkb) ^ swz);
          bfr[fn] = *(const bf16x8*)&smem[byte];
        }
#pragma unroll
        for (int fm = 0; fm < 4; ++fm)
#pragma unroll
          for (int fn = 0; fn < 4; ++fn)
            acc[fm][fn] = __builtin_amdgcn_mfma_f32_16x16x32_bf16(af[fm], bfr[fn], acc[fm][fn], 0, 0, 0);
      }
    }
  }
  // epilogue: col=lane&15, row=(lane>>4)*4+reg
#pragma unroll
  for (int fm = 0; fm < 4; ++fm) {
    int rbase = rowBase + wr * 64 + fm * 16 + ((lane >> 4) << 2);
#pragma unroll
    for (int fn = 0; fn < 4; ++fn) {
      int col = colBase + wc * 64 + fn * 16 + lrow;
      float bb = b1[col] + b2[col];
#pragma unroll
      for (int r = 0; r < 4; ++r) {
        int row = rbase + r;
        if (row >= NN) continue;
        size_t idx = (size_t)row * 512 + col;
        float a = acc[fm][fn][r] + bb;
        if (EPI == 0) {
          outF[idx] = sigmoidf_(a);
        } else if (EPI == 1) {
          outB[idx] = bf16one(H[idx] * sigmoidf_(a));
        } else {
          float t = tanhf(a);
          float z = Z[idx];
          outF[idx] = z * H[idx] + (1.f - z) * t;
        }
      }
    }
  }
}

extern "C" void kernel_launch(void* const* d_in, const int* in_sizes, int n_in,
                              void* d_out, int out_size, void* d_ws, size_t ws_size,
                              hipStream_t stream) {
  const float* X   = (const float*)d_in[0];
  const int*   ei  = (const int*)d_in[1];
  const float* ew  = (const float*)d_in[2];
  const float* H   = (const float*)d_in[3];
  const float* Wxz = (const float*)d_in[4];  const float* bxz = (const float*)d_in[5];
  const float* Whz = (const float*)d_in[6];  const float* bhz = (const float*)d_in[7];
  const float* Wxr = (const float*)d_in[8];  const float* bxr = (const float*)d_in[9];
  const float* Whr = (const float*)d_in[10]; const float* bhr = (const float*)d_in[11];
  const float* Wxh = (const float*)d_in[12]; const float* bxh = (const float*)d_in[13];
  const float* Whh = (const float*)d_in[14]; const float* bhh = (const float*)d_in[15];
  const int* row = ei;
  const int* col = ei + NE;
  float* out = (float*)d_out;

  char* base = (char*)d_ws;
  size_t o = 0;
  auto alloc = [&](size_t b) { char* p = base + o; o += (b + 255) & ~(size_t)255; return p; };
  u16* Xb   = (u16*)alloc((size_t)NN * DD * 2);
  u16* Hb   = (u16*)alloc((size_t)NN * DD * 2);
  u16* AXb  = (u16*)alloc((size_t)NP * DD * 2);
  u16* AHb  = (u16*)alloc((size_t)NP * DD * 2);
  u16* HRb  = (u16*)alloc((size_t)NP * DD * 2);
  u16* AHRb = (u16*)alloc((size_t)NP * DD * 2);
  u16* Wt[6];
  for (int i = 0; i < 6; ++i) Wt[i] = (u16*)alloc((size_t)512 * 512 * 2);
  float* deg  = (float*)alloc(NN * 4);
  float* dinv = (float*)alloc(NN * 4);
  int*   cnt  = (int*)alloc(NN * 4);
  int*   ptr  = (int*)alloc((NN + 1) * 4);
  int*   pos  = (int*)alloc(NN * 4);
  int*   erow = (int*)alloc(NE * 4);
  float* enorm= (float*)alloc(NE * 4);

  dim3 b256(256);
  int gN = (NN + 255) / 256;
  int gE = (NE + 255) / 256;

  // graph normalization + CSR build
  k_init<<<gN, b256, 0, stream>>>(deg, cnt);
  k_accum<<<gE, b256, 0, stream>>>(col, ew, deg, cnt);
  k_dinv<<<gN, b256, 0, stream>>>(deg, dinv);
  k_scan<<<1, 1024, 0, stream>>>(cnt, ptr, pos);
  k_scatter<<<gE, b256, 0, stream>>>(row, col, ew, dinv, pos, erow, enorm);

  // conversions
  int n8 = NN * DD / 8;
  k_cvt_bf16<<<(n8 + 255) / 256, b256, 0, stream>>>(X, Xb, n8);
  k_cvt_bf16<<<(n8 + 255) / 256, b256, 0, stream>>>(H, Hb, n8);
  dim3 wtb(32, 8), wtg(16, 16);
  const float* Ws[6] = {Wxz, Whz, Wxr, Whr, Wxh, Whh};
  for (int i = 0; i < 6; ++i) k_wt<<<wtg, wtb, 0, stream>>>(Ws[i], Wt[i]);

  // AX = Agg(X), AH = Agg(H): XCD-sliced, 8 edges/wave-iter, 16B/lane
  k_agg_dual_s2<<<40000, b256, 0, stream>>>(Xb, Hb, ptr, erow, enorm, dinv, AXb, AHb);

  dim3 gemmGrid(512 / 128, NP / 128);

  // Z = sigmoid(AX@Wxz + AH@Whz + b) -> out (f32)
  k_gemm_mfma<0><<<gemmGrid, b256, 0, stream>>>(AXb, Wt[0], AHb, Wt[1], bxz, bhz,
                                                nullptr, nullptr, out, nullptr);
  // HR = H * sigmoid(AX@Wxr + AH@Whr + b) -> HRb (bf16)
  k_gemm_mfma<1><<<gemmGrid, b256, 0, stream>>>(AXb, Wt[2], AHb, Wt[3], bxr, bhr,
                                                H, nullptr, nullptr, HRb);
  // AHR = Agg(HR)
  k_agg_single_s2<<<40000, b256, 0, stream>>>(HRb, ptr, erow, enorm, dinv, AHRb);

  // out = Z*H + (1-Z)*tanh(AX@Wxh + AHR@Whh + b)
  k_gemm_mfma<2><<<gemmGrid, b256, 0, stream>>>(AXb, Wt[4], AHRb, Wt[5], bxh, bhh,
                                                H, out, out, nullptr);
}

// Round 6
// 417.901 us; speedup vs baseline: 1.3674x; 1.0025x over previous
//
#include <hip/hip_runtime.h>

#define NN 20000
#define NP 20096   // padded rows (multiple of 128)
#define NE 320000
#define DD 512

typedef __bf16 bf16x8 __attribute__((ext_vector_type(8)));
typedef float f32x4 __attribute__((ext_vector_type(4)));
typedef unsigned short u16;

__device__ __forceinline__ float sigmoidf_(float x) { return 1.f / (1.f + expf(-x)); }

__device__ __forceinline__ unsigned bf16pair(float a, float b) {
  unsigned ua = __builtin_bit_cast(unsigned, a);
  unsigned ub = __builtin_bit_cast(unsigned, b);
  ua = (ua + 0x7FFFu + ((ua >> 16) & 1u)) >> 16;
  ub = (ub + 0x7FFFu + ((ub >> 16) & 1u)) >> 16;
  return ua | (ub << 16);
}
__device__ __forceinline__ u16 bf16one(float a) {
  unsigned ua = __builtin_bit_cast(unsigned, a);
  return (u16)((ua + 0x7FFFu + ((ua >> 16) & 1u)) >> 16);
}
__device__ __forceinline__ float bflo(unsigned w) { return __builtin_bit_cast(float, w << 16); }
__device__ __forceinline__ float bfhi(unsigned w) { return __builtin_bit_cast(float, w & 0xFFFF0000u); }
__device__ __forceinline__ float bf2f(u16 v) { return __builtin_bit_cast(float, (unsigned)v << 16); }

__device__ __forceinline__ void gload16(const void* g, void* l) {
  __builtin_amdgcn_global_load_lds(
      (const __attribute__((address_space(1))) unsigned int*)g,
      (__attribute__((address_space(3))) unsigned int*)l, 16, 0, 0);
}

// ---------------- degree / norm / CSR ----------------
__global__ void k_init(float* deg, int* cnt) {
  int i = blockIdx.x * 256 + threadIdx.x;
  if (i < NN) { deg[i] = 1.0f; cnt[i] = 0; }
}

__global__ void k_accum(const int* col, const float* w, float* deg, int* cnt) {
  int e = blockIdx.x * 256 + threadIdx.x;
  if (e < NE) {
    int c = col[e];
    atomicAdd(&deg[c], w[e]);
    atomicAdd(&cnt[c], 1);
  }
}

__global__ void k_dinv(const float* deg, float* dinv) {
  int i = blockIdx.x * 256 + threadIdx.x;
  if (i < NN) dinv[i] = rsqrtf(deg[i]);
}

__global__ void k_scan(const int* cnt, int* ptr, int* pos) {
  __shared__ int sdata[1024];
  const int ITEMS = (NN + 1023) / 1024;
  int tid = threadIdx.x;
  int base = tid * ITEMS;
  int s = 0;
  for (int j = 0; j < ITEMS; ++j) { int i = base + j; if (i < NN) s += cnt[i]; }
  sdata[tid] = s;
  __syncthreads();
  for (int off = 1; off < 1024; off <<= 1) {
    int v = 0;
    if (tid >= off) v = sdata[tid - off];
    __syncthreads();
    sdata[tid] += v;
    __syncthreads();
  }
  int run = (tid == 0) ? 0 : sdata[tid - 1];
  for (int j = 0; j < ITEMS; ++j) {
    int i = base + j;
    if (i < NN) { ptr[i] = run; pos[i] = run; run += cnt[i]; }
  }
  if (tid == 0) ptr[NN] = NE;
}

__global__ void k_scatter(const int* row, const int* col, const float* w, const float* dinv,
                          int* pos, int* erow, float* enorm) {
  int e = blockIdx.x * 256 + threadIdx.x;
  if (e < NE) {
    int r = row[e], c = col[e];
    int slot = atomicAdd(&pos[c], 1);
    erow[slot] = r;
    enorm[slot] = dinv[r] * w[e] * dinv[c];
  }
}

// ---------------- conversions ----------------
__global__ void k_cvt_bf16(const float* __restrict__ src, u16* __restrict__ dst, int n8) {
  int i = blockIdx.x * 256 + threadIdx.x;
  if (i >= n8) return;
  const float4* s = (const float4*)src;
  float4 v0 = s[i * 2], v1 = s[i * 2 + 1];
  uint4 o;
  o.x = bf16pair(v0.x, v0.y);
  o.y = bf16pair(v0.z, v0.w);
  o.z = bf16pair(v1.x, v1.y);
  o.w = bf16pair(v1.z, v1.w);
  ((uint4*)dst)[i] = o;
}

// W [512][512] f32 -> Wt [n][k] bf16 (transposed)
__global__ void k_wt(const float* __restrict__ W, u16* __restrict__ Wt) {
  __shared__ float t[32][33];
  int tx = threadIdx.x, ty = threadIdx.y;  // (32,8)
  int kb = blockIdx.x * 32, nb = blockIdx.y * 32;
#pragma unroll
  for (int i = 0; i < 4; ++i)
    t[ty * 4 + i][tx] = W[(size_t)(kb + ty * 4 + i) * 512 + nb + tx];
  __syncthreads();
#pragma unroll
  for (int i = 0; i < 4; ++i)
    Wt[(size_t)(nb + ty * 4 + i) * 512 + kb + tx] = bf16one(t[tx][ty * 4 + i]);
}

// ---------------- XCD-sliced aggregation, 16B/lane, stride-8 edge loop ----------
// slice = bid&7; wave = one node. lane = g*8+cl; group g handles items g, g+8, ...
// item 0 = self-loop (weight dinv^2), item i>0 = CSR edge pe+i-1.
// Tail: shfl_xor butterfly (8/16/32) sums the 8 groups.
__global__ __launch_bounds__(256) void k_agg_dual_s2(const u16* __restrict__ Xb,
                                                     const u16* __restrict__ Hb,
                                                     const int* __restrict__ ptr,
                                                     const int* __restrict__ erow,
                                                     const float* __restrict__ enorm,
                                                     const float* __restrict__ dinv,
                                                     u16* __restrict__ AXb,
                                                     u16* __restrict__ AHb) {
  int bid = blockIdx.x;
  int slice = bid & 7, nb = bid >> 3;
  int w = threadIdx.x >> 6, lane = threadIdx.x & 63;
  int node = nb * 4 + w;
  int g = lane >> 3, cl = lane & 7;
  int soff = slice * 8 + cl;                 // uint4 index within a 64-uint4 row
  const uint4* X4 = (const uint4*)Xb;
  const uint4* H4 = (const uint4*)Hb;
  float s = dinv[node], s2 = s * s;
  int pe = ptr[node];
  int items = ptr[node + 1] - pe + 1;        // self + deg

  float ax[8] = {}, ah[8] = {};
  auto accum = [&](float nm, uint4 xv, uint4 hv) {
    unsigned xw[4] = {xv.x, xv.y, xv.z, xv.w};
    unsigned hw[4] = {hv.x, hv.y, hv.z, hv.w};
#pragma unroll
    for (int j = 0; j < 4; ++j) {
      ax[2 * j]     += nm * bflo(xw[j]);
      ax[2 * j + 1] += nm * bfhi(xw[j]);
      ah[2 * j]     += nm * bflo(hw[j]);
      ah[2 * j + 1] += nm * bfhi(hw[j]);
    }
  };

  for (int it = g; it < items; it += 8) {
    int r = node; float nm = s2;
    if (it > 0) { r = erow[pe + it - 1]; nm = enorm[pe + it - 1]; }
    uint4 xv = X4[(size_t)r * 64 + soff];
    uint4 hv = H4[(size_t)r * 64 + soff];
    accum(nm, xv, hv);
  }

#pragma unroll
  for (int st = 8; st < 64; st <<= 1) {
#pragma unroll
    for (int j = 0; j < 8; ++j) {
      ax[j] += __shfl_xor(ax[j], st, 64);
      ah[j] += __shfl_xor(ah[j], st, 64);
    }
  }

  if (g == 0) {
    uint4 ox;
    ox.x = bf16pair(ax[0], ax[1]); ox.y = bf16pair(ax[2], ax[3]);
    ox.z = bf16pair(ax[4], ax[5]); ox.w = bf16pair(ax[6], ax[7]);
    ((uint4*)AXb)[(size_t)node * 64 + soff] = ox;
  } else if (g == 1) {
    uint4 oh;
    oh.x = bf16pair(ah[0], ah[1]); oh.y = bf16pair(ah[2], ah[3]);
    oh.z = bf16pair(ah[4], ah[5]); oh.w = bf16pair(ah[6], ah[7]);
    ((uint4*)AHb)[(size_t)node * 64 + soff] = oh;
  }
}

__global__ __launch_bounds__(256) void k_agg_single_s2(const u16* __restrict__ Sb,
                                                       const int* __restrict__ ptr,
                                                       const int* __restrict__ erow,
                                                       const float* __restrict__ enorm,
                                                       const float* __restrict__ dinv,
                                                       u16* __restrict__ Ab) {
  int bid = blockIdx.x;
  int slice = bid & 7, nb = bid >> 3;
  int w = threadIdx.x >> 6, lane = threadIdx.x & 63;
  int node = nb * 4 + w;
  int g = lane >> 3, cl = lane & 7;
  int soff = slice * 8 + cl;
  const uint4* S4 = (const uint4*)Sb;
  float s = dinv[node], s2 = s * s;
  int pe = ptr[node];
  int items = ptr[node + 1] - pe + 1;

  float ax[8] = {};
  auto accum = [&](float nm, uint4 xv) {
    unsigned xw[4] = {xv.x, xv.y, xv.z, xv.w};
#pragma unroll
    for (int j = 0; j < 4; ++j) {
      ax[2 * j]     += nm * bflo(xw[j]);
      ax[2 * j + 1] += nm * bfhi(xw[j]);
    }
  };

  for (int it = g; it < items; it += 8) {
    int r = node; float nm = s2;
    if (it > 0) { r = erow[pe + it - 1]; nm = enorm[pe + it - 1]; }
    accum(nm, S4[(size_t)r * 64 + soff]);
  }

#pragma unroll
  for (int st = 8; st < 64; st <<= 1) {
#pragma unroll
    for (int j = 0; j < 8; ++j) ax[j] += __shfl_xor(ax[j], st, 64);
  }

  if (g == 0) {
    uint4 ox;
    ox.x = bf16pair(ax[0], ax[1]); ox.y = bf16pair(ax[2], ax[3]);
    ox.z = bf16pair(ax[4], ax[5]); ox.w = bf16pair(ax[6], ax[7]);
    ((uint4*)Ab)[(size_t)node * 64 + soff] = ox;
  }
}

// ---------------- MFMA GEMM + fused epilogue, XCD-chunked block map ----------
// grid = 628 1-D blocks; bijective chunk map (m204) keeps the 4 col-blocks of
// each 128-row block on ONE XCD -> A fetched once per row, not 4x.
// EPI 0: Zb = bf16(sigmoid(acc+b1+b2))
// EPI 1: HRb = bf16(H * sigmoid(acc+b1+b2))
// EPI 2: outF = z*H + (1-z)*tanh(acc+b1+b2), z = bf2f(Zr)
template <int EPI>
__global__ __launch_bounds__(256) void k_gemm_mfma(
    const u16* __restrict__ A1, const u16* __restrict__ W1t,
    const u16* __restrict__ A2, const u16* __restrict__ W2t,
    const float* __restrict__ b1, const float* __restrict__ b2,
    const float* __restrict__ H, const u16* __restrict__ Zr,
    float* __restrict__ outF, u16* __restrict__ outB) {
  __shared__ unsigned char smem[32768];  // As 16KB | Bs 16KB
  const int tid = threadIdx.x;
  const int lane = tid & 63, w = tid >> 6;
  const int wr = w >> 1, wc = w & 1;

  // bijective XCD-chunked mapping: NB=628 blocks, 4 col-blocks per row-block
  const int NB = 628, q = NB >> 3, r8 = NB & 7;  // 78, 4
  const int xcd = blockIdx.x & 7, ii = blockIdx.x >> 3;
  const int start = (xcd < r8) ? xcd * (q + 1) : r8 * (q + 1) + (xcd - r8) * q;
  const int wk = start + ii;
  const int rowBase = (wk >> 2) * 128;
  const int colBase = (wk & 3) * 128;

  f32x4 acc[4][4] = {};

  const int lrow = lane & 15;
  const int lkb = (lane >> 4) << 4;
  const int swz = (lane & 7) << 4;
  const int srow = w * 32 + (lane >> 3);
  const int scol = (((lane & 7) ^ (lane >> 3)) << 4);

  for (int pass = 0; pass < 2; ++pass) {
    const u16* A = pass ? A2 : A1;
    const u16* Wt = pass ? W2t : W1t;
    const char* Abase = (const char*)A + (size_t)(rowBase + srow) * 1024 + scol;
    const char* Bbase = (const char*)Wt + (size_t)(colBase + srow) * 1024 + scol;
    for (int k0 = 0; k0 < 512; k0 += 64) {
      __syncthreads();
#pragma unroll
      for (int t = 0; t < 4; ++t) {
        gload16(Abase + (size_t)t * 8192 + k0 * 2, &smem[w * 4096 + t * 1024]);
        gload16(Bbase + (size_t)t * 8192 + k0 * 2, &smem[16384 + w * 4096 + t * 1024]);
      }
      __syncthreads();
#pragma unroll
      for (int ks = 0; ks < 2; ++ks) {
        bf16x8 af[4], bfr[4];
#pragma unroll
        for (int fm = 0; fm < 4; ++fm) {
          int row = wr * 64 + fm * 16 + lrow;
          int byte = row * 128 + (((ks << 6) + lkb) ^ swz);
          af[fm] = *(const bf16x8*)&smem[byte];
        }
#pragma unroll
        for (int fn = 0; fn < 4; ++fn) {
          int row = wc * 64 + fn * 16 + lrow;
          int byte = 16384 + row * 128 + (((ks << 6) + lkb) ^ swz);
          bfr[fn] = *(const bf16x8*)&smem[byte];
        }
#pragma unroll
        for (int fm = 0; fm < 4; ++fm)
#pragma unroll
          for (int fn = 0; fn < 4; ++fn)
            acc[fm][fn] = __builtin_amdgcn_mfma_f32_16x16x32_bf16(af[fm], bfr[fn], acc[fm][fn], 0, 0, 0);
      }
    }
  }
  // epilogue: col=lane&15, row=(lane>>4)*4+reg
#pragma unroll
  for (int fm = 0; fm < 4; ++fm) {
    int rbase = rowBase + wr * 64 + fm * 16 + ((lane >> 4) << 2);
#pragma unroll
    for (int fn = 0; fn < 4; ++fn) {
      int col = colBase + wc * 64 + fn * 16 + lrow;
      float bb = b1[col] + b2[col];
#pragma unroll
      for (int r = 0; r < 4; ++r) {
        int row = rbase + r;
        if (row >= NN) continue;
        size_t idx = (size_t)row * 512 + col;
        float a = acc[fm][fn][r] + bb;
        if (EPI == 0) {
          outB[idx] = bf16one(sigmoidf_(a));
        } else if (EPI == 1) {
          outB[idx] = bf16one(H[idx] * sigmoidf_(a));
        } else {
          float t = tanhf(a);
          float z = bf2f(Zr[idx]);
          outF[idx] = z * H[idx] + (1.f - z) * t;
        }
      }
    }
  }
}

extern "C" void kernel_launch(void* const* d_in, const int* in_sizes, int n_in,
                              void* d_out, int out_size, void* d_ws, size_t ws_size,
                              hipStream_t stream) {
  const float* X   = (const float*)d_in[0];
  const int*   ei  = (const int*)d_in[1];
  const float* ew  = (const float*)d_in[2];
  const float* H   = (const float*)d_in[3];
  const float* Wxz = (const float*)d_in[4];  const float* bxz = (const float*)d_in[5];
  const float* Whz = (const float*)d_in[6];  const float* bhz = (const float*)d_in[7];
  const float* Wxr = (const float*)d_in[8];  const float* bxr = (const float*)d_in[9];
  const float* Whr = (const float*)d_in[10]; const float* bhr = (const float*)d_in[11];
  const float* Wxh = (const float*)d_in[12]; const float* bxh = (const float*)d_in[13];
  const float* Whh = (const float*)d_in[14]; const float* bhh = (const float*)d_in[15];
  const int* row = ei;
  const int* col = ei + NE;
  float* out = (float*)d_out;

  char* base = (char*)d_ws;
  size_t o = 0;
  auto alloc = [&](size_t b) { char* p = base + o; o += (b + 255) & ~(size_t)255; return p; };
  u16* Xb   = (u16*)alloc((size_t)NN * DD * 2);
  u16* Hb   = (u16*)alloc((size_t)NN * DD * 2);
  u16* AXb  = (u16*)alloc((size_t)NP * DD * 2);
  u16* AHb  = (u16*)alloc((size_t)NP * DD * 2);
  u16* HRb  = (u16*)alloc((size_t)NP * DD * 2);
  u16* AHRb = (u16*)alloc((size_t)NP * DD * 2);
  u16* Zb   = (u16*)alloc((size_t)NP * DD * 2);
  u16* Wt[6];
  for (int i = 0; i < 6; ++i) Wt[i] = (u16*)alloc((size_t)512 * 512 * 2);
  float* deg  = (float*)alloc(NN * 4);
  float* dinv = (float*)alloc(NN * 4);
  int*   cnt  = (int*)alloc(NN * 4);
  int*   ptr  = (int*)alloc((NN + 1) * 4);
  int*   pos  = (int*)alloc(NN * 4);
  int*   erow = (int*)alloc(NE * 4);
  float* enorm= (float*)alloc(NE * 4);

  dim3 b256(256);
  int gN = (NN + 255) / 256;
  int gE = (NE + 255) / 256;

  // graph normalization + CSR build
  k_init<<<gN, b256, 0, stream>>>(deg, cnt);
  k_accum<<<gE, b256, 0, stream>>>(col, ew, deg, cnt);
  k_dinv<<<gN, b256, 0, stream>>>(deg, dinv);
  k_scan<<<1, 1024, 0, stream>>>(cnt, ptr, pos);
  k_scatter<<<gE, b256, 0, stream>>>(row, col, ew, dinv, pos, erow, enorm);

  // conversions
  int n8 = NN * DD / 8;
  k_cvt_bf16<<<(n8 + 255) / 256, b256, 0, stream>>>(X, Xb, n8);
  k_cvt_bf16<<<(n8 + 255) / 256, b256, 0, stream>>>(H, Hb, n8);
  dim3 wtb(32, 8), wtg(16, 16);
  const float* Ws[6] = {Wxz, Whz, Wxr, Whr, Wxh, Whh};
  for (int i = 0; i < 6; ++i) k_wt<<<wtg, wtb, 0, stream>>>(Ws[i], Wt[i]);

  // AX = Agg(X), AH = Agg(H): XCD-sliced, stride-8 edge loop, 16B/lane
  k_agg_dual_s2<<<40000, b256, 0, stream>>>(Xb, Hb, ptr, erow, enorm, dinv, AXb, AHb);

  // Z = bf16(sigmoid(AX@Wxz + AH@Whz + b)) -> Zb
  k_gemm_mfma<0><<<628, b256, 0, stream>>>(AXb, Wt[0], AHb, Wt[1], bxz, bhz,
                                           nullptr, nullptr, nullptr, Zb);
  // HR = bf16(H * sigmoid(AX@Wxr + AH@Whr + b)) -> HRb
  k_gemm_mfma<1><<<628, b256, 0, stream>>>(AXb, Wt[2], AHb, Wt[3], bxr, bhr,
                                           H, nullptr, nullptr, HRb);
  // AHR = Agg(HR)
  k_agg_single_s2<<<40000, b256, 0, stream>>>(HRb, ptr, erow, enorm, dinv, AHRb);

  // out = Z*H + (1-Z)*tanh(AX@Wxh + AHR@Whh + b)
  k_gemm_mfma<2><<<628, b256, 0, stream>>>(AXb, Wt[4], AHRb, Wt[5], bxh, bhh,
                                           H, Zb, out, nullptr);
}